// Round 1
// baseline (545.549 us; speedup 1.0000x reference)
//
#include <hip/hip_runtime.h>
#include <hip/hip_bf16.h>

#define NB 4
#define NS 2048
#define ND 1024
#define NH 16
#define NHD 64
#define NM (NB*NS)   // 8192 rows of X

typedef __bf16 bf16_t;
typedef bf16_t bf8  __attribute__((ext_vector_type(8)));
typedef bf16_t bf4v __attribute__((ext_vector_type(4)));
typedef float  f4   __attribute__((ext_vector_type(4)));

// ---------------- fp32 -> bf16 conversion ----------------
__global__ __launch_bounds__(256) void cvt_kernel(const float* __restrict__ src,
                                                  bf16_t* __restrict__ dst, int n4) {
    int i = blockIdx.x * 256 + threadIdx.x;
    if (i < n4) {
        const float4 v = ((const float4*)src)[i];
        bf4v o;
        o[0] = (bf16_t)v.x; o[1] = (bf16_t)v.y; o[2] = (bf16_t)v.z; o[3] = (bf16_t)v.w;
        ((bf4v*)dst)[i] = o;
    }
}

// ---------------- fused QKV GEMM ----------------
// C[M=8192, N=3072] = X[8192,1024] @ Wqkv^T  (Wqkv stored [3072,1024] row-major, K inner)
// epilogue: + bias, scatter to Q/K/V in [B,H,S,hd] bf16 layout
__global__ __launch_bounds__(256) void gemm_qkv(const bf16_t* __restrict__ A,
                                                const bf16_t* __restrict__ Bw,
                                                const float* __restrict__ bq,
                                                const float* __restrict__ bk,
                                                const float* __restrict__ bv,
                                                bf16_t* __restrict__ Qh,
                                                bf16_t* __restrict__ Kh,
                                                bf16_t* __restrict__ Vh) {
    __shared__ __align__(16) bf16_t As[128 * 40];   // 128 rows x 32 k, padded to 40
    __shared__ __align__(16) bf16_t Bs[128 * 40];
    const int t = threadIdx.x;
    const int wave = t >> 6, lane = t & 63, ln = lane & 15, quad = lane >> 4;
    const int wm = (wave >> 1) * 64, wn = (wave & 1) * 64;
    const int m0 = blockIdx.y * 128, n0 = blockIdx.x * 128;
    const int K = 1024;

    f4 acc[4][4];
    const f4 z = {0.f, 0.f, 0.f, 0.f};
#pragma unroll
    for (int i = 0; i < 4; ++i)
#pragma unroll
        for (int j = 0; j < 4; ++j) acc[i][j] = z;

    const int sr = t >> 2, sc = (t & 3) * 8;
    for (int k0 = 0; k0 < K; k0 += 32) {
        __syncthreads();
        *(uint4*)(&As[sr * 40 + sc])        = *(const uint4*)(&A[(size_t)(m0 + sr) * K + k0 + sc]);
        *(uint4*)(&As[(sr + 64) * 40 + sc]) = *(const uint4*)(&A[(size_t)(m0 + sr + 64) * K + k0 + sc]);
        *(uint4*)(&Bs[sr * 40 + sc])        = *(const uint4*)(&Bw[(size_t)(n0 + sr) * K + k0 + sc]);
        *(uint4*)(&Bs[(sr + 64) * 40 + sc]) = *(const uint4*)(&Bw[(size_t)(n0 + sr + 64) * K + k0 + sc]);
        __syncthreads();
        bf8 af[4], bfr[4];
#pragma unroll
        for (int mt = 0; mt < 4; ++mt) af[mt]  = *(const bf8*)(&As[(wm + mt * 16 + ln) * 40 + quad * 8]);
#pragma unroll
        for (int nt = 0; nt < 4; ++nt) bfr[nt] = *(const bf8*)(&Bs[(wn + nt * 16 + ln) * 40 + quad * 8]);
#pragma unroll
        for (int mt = 0; mt < 4; ++mt)
#pragma unroll
            for (int nt = 0; nt < 4; ++nt)
                acc[mt][nt] = __builtin_amdgcn_mfma_f32_16x16x32_bf16(af[mt], bfr[nt], acc[mt][nt], 0, 0, 0);
    }

#pragma unroll
    for (int nt = 0; nt < 4; ++nt) {
        const int gn = n0 + wn + nt * 16 + ln;
        const int sec = gn >> 10, nn = gn & 1023;
        const int h = nn >> 6, d = nn & 63;
        const float bias = (sec == 0 ? bq[nn] : (sec == 1 ? bk[nn] : bv[nn]));
        bf16_t* dstBase = (sec == 0 ? Qh : (sec == 1 ? Kh : Vh));
#pragma unroll
        for (int mt = 0; mt < 4; ++mt) {
#pragma unroll
            for (int r = 0; r < 4; ++r) {
                const int gm = m0 + wm + mt * 16 + quad * 4 + r;
                const int b = gm >> 11, s = gm & 2047;
                dstBase[((size_t)(b * NH + h) * NS + s) * NHD + d] = (bf16_t)(acc[mt][nt][r] + bias);
            }
        }
    }
}

// ---------------- flash attention ----------------
// grid: (S/64 q-tiles, B*H). block 256 = 4 waves; each wave owns 16 q-rows.
__global__ __launch_bounds__(256) void attn_kernel(const bf16_t* __restrict__ Q,
                                                   const bf16_t* __restrict__ K,
                                                   const bf16_t* __restrict__ V,
                                                   bf16_t* __restrict__ O) {
    __shared__ __align__(16) bf16_t Ks[64 * 72];       // [kv][d], padded
    __shared__ __align__(16) bf16_t Vt[64 * 72];       // [d][kv], padded
    __shared__ __align__(16) bf16_t Ps[4][16 * 72];    // per-wave P strip [row][kv]
    const int qt = blockIdx.x;
    const int bh = blockIdx.y;
    const int q0 = qt * 64;
    const size_t head_off = (size_t)bh * NS * NHD;
    const int t = threadIdx.x;
    const int wave = t >> 6, lane = t & 63, ln = lane & 15, quad = lane >> 4;

    // per-wave Q strip fragments (A-layout): rows q0+wave*16+ln, k = d
    const bf16_t* Qrow = Q + head_off + (size_t)(q0 + wave * 16 + ln) * NHD;
    const bf8 qf0 = *(const bf8*)(Qrow + quad * 8);
    const bf8 qf1 = *(const bf8*)(Qrow + 32 + quad * 8);

    f4 o[4];
    const f4 z = {0.f, 0.f, 0.f, 0.f};
#pragma unroll
    for (int i = 0; i < 4; ++i) o[i] = z;
    float mrow[4], lrow[4];
#pragma unroll
    for (int r = 0; r < 4; ++r) { mrow[r] = -1e30f; lrow[r] = 0.f; }

    for (int j = 0; j <= qt; ++j) {
        const int kv0 = j * 64;
        __syncthreads();  // previous iteration's reads of Ks/Vt complete
        {
            const bf16_t* Kg = K + head_off + (size_t)kv0 * NHD;
            const bf16_t* Vg = V + head_off + (size_t)kv0 * NHD;
            int c = t;
            *(uint4*)(&Ks[(c >> 3) * 72 + (c & 7) * 8]) = *(const uint4*)(Kg + (c >> 3) * 64 + (c & 7) * 8);
            {
                const int kv = c >> 3, d0 = (c & 7) * 8;
                const bf8 vv = *(const bf8*)(Vg + kv * 64 + d0);
#pragma unroll
                for (int e = 0; e < 8; ++e) Vt[(d0 + e) * 72 + kv] = vv[e];
            }
            c = t + 256;
            *(uint4*)(&Ks[(c >> 3) * 72 + (c & 7) * 8]) = *(const uint4*)(Kg + (c >> 3) * 64 + (c & 7) * 8);
            {
                const int kv = c >> 3, d0 = (c & 7) * 8;
                const bf8 vv = *(const bf8*)(Vg + kv * 64 + d0);
#pragma unroll
                for (int e = 0; e < 8; ++e) Vt[(d0 + e) * 72 + kv] = vv[e];
            }
        }
        __syncthreads();

        // S = Q @ K^T (per wave: 16 x 64 strip, 4 col-tiles)
        f4 s[4];
#pragma unroll
        for (int nt = 0; nt < 4; ++nt) {
            s[nt] = z;
            const bf8 kf0 = *(const bf8*)(&Ks[(nt * 16 + ln) * 72 + quad * 8]);
            const bf8 kf1 = *(const bf8*)(&Ks[(nt * 16 + ln) * 72 + 32 + quad * 8]);
            s[nt] = __builtin_amdgcn_mfma_f32_16x16x32_bf16(qf0, kf0, s[nt], 0, 0, 0);
            s[nt] = __builtin_amdgcn_mfma_f32_16x16x32_bf16(qf1, kf1, s[nt], 0, 0, 0);
        }

        // scale + causal mask + row max
        const int rowg = q0 + wave * 16 + quad * 4;  // + r
        float tmax[4] = {-1e30f, -1e30f, -1e30f, -1e30f};
        const bool diag = (j == qt);
#pragma unroll
        for (int nt = 0; nt < 4; ++nt) {
            const int col = kv0 + nt * 16 + ln;
#pragma unroll
            for (int r = 0; r < 4; ++r) {
                float v = s[nt][r] * 0.125f;
                if (diag && col > rowg + r) v = -1e30f;
                s[nt][r] = v;
                tmax[r] = fmaxf(tmax[r], v);
            }
        }
#pragma unroll
        for (int off = 1; off < 16; off <<= 1)
#pragma unroll
            for (int r = 0; r < 4; ++r) tmax[r] = fmaxf(tmax[r], __shfl_xor(tmax[r], off));

        float alpha[4];
#pragma unroll
        for (int r = 0; r < 4; ++r) {
            const float mnew = fmaxf(mrow[r], tmax[r]);
            alpha[r] = __expf(mrow[r] - mnew);
            mrow[r] = mnew;
        }
        float tsum[4] = {0.f, 0.f, 0.f, 0.f};
#pragma unroll
        for (int nt = 0; nt < 4; ++nt)
#pragma unroll
            for (int r = 0; r < 4; ++r) {
                const float p = __expf(s[nt][r] - mrow[r]);
                s[nt][r] = p;
                tsum[r] += p;
            }
#pragma unroll
        for (int off = 1; off < 16; off <<= 1)
#pragma unroll
            for (int r = 0; r < 4; ++r) tsum[r] += __shfl_xor(tsum[r], off);
#pragma unroll
        for (int r = 0; r < 4; ++r) lrow[r] = lrow[r] * alpha[r] + tsum[r];
#pragma unroll
        for (int dt = 0; dt < 4; ++dt)
#pragma unroll
            for (int r = 0; r < 4; ++r) o[dt][r] *= alpha[r];

        // P (C-layout) -> LDS, then re-read as A-layout
        bf16_t* Pw = &Ps[wave][0];
#pragma unroll
        for (int nt = 0; nt < 4; ++nt)
#pragma unroll
            for (int r = 0; r < 4; ++r)
                Pw[(quad * 4 + r) * 72 + nt * 16 + ln] = (bf16_t)s[nt][r];
        __syncthreads();

        const bf8 p0 = *(const bf8*)(&Pw[ln * 72 + quad * 8]);
        const bf8 p1 = *(const bf8*)(&Pw[ln * 72 + 32 + quad * 8]);
#pragma unroll
        for (int dt = 0; dt < 4; ++dt) {
            const bf8 v0 = *(const bf8*)(&Vt[(dt * 16 + ln) * 72 + quad * 8]);
            const bf8 v1 = *(const bf8*)(&Vt[(dt * 16 + ln) * 72 + 32 + quad * 8]);
            o[dt] = __builtin_amdgcn_mfma_f32_16x16x32_bf16(p0, v0, o[dt], 0, 0, 0);
            o[dt] = __builtin_amdgcn_mfma_f32_16x16x32_bf16(p1, v1, o[dt], 0, 0, 0);
        }
    }

    // epilogue: O /= l, store to [b][s][h*64+d] bf16
    const int b = bh >> 4, h = bh & 15;
#pragma unroll
    for (int r = 0; r < 4; ++r) {
        const float inv = 1.f / lrow[r];
        const int gs = q0 + wave * 16 + quad * 4 + r;
#pragma unroll
        for (int dt = 0; dt < 4; ++dt)
            O[((size_t)(b * NS + gs)) * ND + h * NHD + dt * 16 + ln] = (bf16_t)(o[dt][r] * inv);
    }
}

// ---------------- output projection GEMM ----------------
// out[8192,1024] = AO[8192,1024] @ Wo^T + bo + comp  (fp32 out)
__global__ __launch_bounds__(256) void gemm_proj(const bf16_t* __restrict__ A,
                                                 const bf16_t* __restrict__ Bw,
                                                 const float* __restrict__ bo,
                                                 const float* __restrict__ comp,
                                                 float* __restrict__ out) {
    __shared__ __align__(16) bf16_t As[128 * 40];
    __shared__ __align__(16) bf16_t Bs[128 * 40];
    const int t = threadIdx.x;
    const int wave = t >> 6, lane = t & 63, ln = lane & 15, quad = lane >> 4;
    const int wm = (wave >> 1) * 64, wn = (wave & 1) * 64;
    const int m0 = blockIdx.y * 128, n0 = blockIdx.x * 128;
    const int K = 1024;

    f4 acc[4][4];
    const f4 z = {0.f, 0.f, 0.f, 0.f};
#pragma unroll
    for (int i = 0; i < 4; ++i)
#pragma unroll
        for (int j = 0; j < 4; ++j) acc[i][j] = z;

    const int sr = t >> 2, sc = (t & 3) * 8;
    for (int k0 = 0; k0 < K; k0 += 32) {
        __syncthreads();
        *(uint4*)(&As[sr * 40 + sc])        = *(const uint4*)(&A[(size_t)(m0 + sr) * K + k0 + sc]);
        *(uint4*)(&As[(sr + 64) * 40 + sc]) = *(const uint4*)(&A[(size_t)(m0 + sr + 64) * K + k0 + sc]);
        *(uint4*)(&Bs[sr * 40 + sc])        = *(const uint4*)(&Bw[(size_t)(n0 + sr) * K + k0 + sc]);
        *(uint4*)(&Bs[(sr + 64) * 40 + sc]) = *(const uint4*)(&Bw[(size_t)(n0 + sr + 64) * K + k0 + sc]);
        __syncthreads();
        bf8 af[4], bfr[4];
#pragma unroll
        for (int mt = 0; mt < 4; ++mt) af[mt]  = *(const bf8*)(&As[(wm + mt * 16 + ln) * 40 + quad * 8]);
#pragma unroll
        for (int nt = 0; nt < 4; ++nt) bfr[nt] = *(const bf8*)(&Bs[(wn + nt * 16 + ln) * 40 + quad * 8]);
#pragma unroll
        for (int mt = 0; mt < 4; ++mt)
#pragma unroll
            for (int nt = 0; nt < 4; ++nt)
                acc[mt][nt] = __builtin_amdgcn_mfma_f32_16x16x32_bf16(af[mt], bfr[nt], acc[mt][nt], 0, 0, 0);
    }

#pragma unroll
    for (int nt = 0; nt < 4; ++nt) {
        const int gn = n0 + wn + nt * 16 + ln;
        const float bias = bo[gn] + comp[gn];
#pragma unroll
        for (int mt = 0; mt < 4; ++mt) {
#pragma unroll
            for (int r = 0; r < 4; ++r) {
                const int gm = m0 + wm + mt * 16 + quad * 4 + r;
                out[(size_t)gm * ND + gn] = acc[mt][nt][r] + bias;
            }
        }
    }
}

extern "C" void kernel_launch(void* const* d_in, const int* in_sizes, int n_in,
                              void* d_out, int out_size, void* d_ws, size_t ws_size,
                              hipStream_t stream) {
    const float* x    = (const float*)d_in[0];
    const float* Wq   = (const float*)d_in[1];
    const float* bq   = (const float*)d_in[2];
    const float* Wk   = (const float*)d_in[3];
    const float* bk   = (const float*)d_in[4];
    const float* Wv   = (const float*)d_in[5];
    const float* bv   = (const float*)d_in[6];
    const float* Wo   = (const float*)d_in[7];
    const float* bo   = (const float*)d_in[8];
    const float* comp = (const float*)d_in[9];
    float* out = (float*)d_out;

    char* w = (char*)d_ws;
    bf16_t* Xb   = (bf16_t*)(w);                         // 8192x1024
    bf16_t* Wqkv = (bf16_t*)(w + 16777216);              // 3072x1024
    bf16_t* Wob  = (bf16_t*)(w + 23068672);              // 1024x1024
    bf16_t* Qh   = (bf16_t*)(w + 25165824);              // [B,H,S,hd]
    bf16_t* Kh   = (bf16_t*)(w + 41943040);
    bf16_t* Vh   = (bf16_t*)(w + 58720256);
    bf16_t* AOb  = (bf16_t*)(w + 75497472);              // 8192x1024

    const int nX = NM * ND;       // 8388608
    const int nW = ND * ND;       // 1048576
    cvt_kernel<<<(nX / 4 + 255) / 256, 256, 0, stream>>>(x, Xb, nX / 4);
    cvt_kernel<<<(nW / 4 + 255) / 256, 256, 0, stream>>>(Wq, Wqkv, nW / 4);
    cvt_kernel<<<(nW / 4 + 255) / 256, 256, 0, stream>>>(Wk, Wqkv + nW, nW / 4);
    cvt_kernel<<<(nW / 4 + 255) / 256, 256, 0, stream>>>(Wv, Wqkv + 2 * nW, nW / 4);
    cvt_kernel<<<(nW / 4 + 255) / 256, 256, 0, stream>>>(Wo, Wob, nW / 4);

    gemm_qkv<<<dim3(3072 / 128, NM / 128), 256, 0, stream>>>(Xb, Wqkv, bq, bk, bv, Qh, Kh, Vh);
    attn_kernel<<<dim3(NS / 64, NB * NH), 256, 0, stream>>>(Qh, Kh, Vh, AOb);
    gemm_proj<<<dim3(1024 / 128, NM / 128), 256, 0, stream>>>(AOb, Wob, bo, comp, out);
}